// Round 12
// baseline (228.022 us; speedup 1.0000x reference)
//
#include <hip/hip_runtime.h>

typedef unsigned short u16;
typedef short short8 __attribute__((ext_vector_type(8)));
typedef float floatx4 __attribute__((ext_vector_type(4)));

#define MFMA16(a, b, c) __builtin_amdgcn_mfma_f32_16x16x32_bf16((a), (b), (c), 0, 0, 0)

__device__ __forceinline__ u16 f2bf(float f) {
  unsigned u = __builtin_bit_cast(unsigned, f);
  u = (u + 0x7fffu + ((u >> 16) & 1u)) >> 16;
  return (u16)u;
}

__device__ __forceinline__ float bf2f(u16 u) {
  return __builtin_bit_cast(float, ((unsigned)u) << 16);
}

__device__ __forceinline__ float exp2hw(float x) {
  float r; asm("v_exp_f32 %0, %1" : "=v"(r) : "v"(x)); return r;
}

__device__ __forceinline__ unsigned cvtpk_bf16(float lo, float hi) {
  unsigned r;
  asm("v_cvt_pk_bf16_f32 %0, %1, %2" : "=v"(r) : "v"(lo), "v"(hi));
  return r;
}

__device__ __forceinline__ float bflo(unsigned u) {
  return __builtin_bit_cast(float, u << 16);
}
__device__ __forceinline__ float bfhi(unsigned u) {
  return __builtin_bit_cast(float, u & 0xffff0000u);
}

__device__ __forceinline__ void gload16(const void* g, void* l) {
  typedef __attribute__((address_space(1))) const void GV;
  typedef __attribute__((address_space(3))) void LV;
  __builtin_amdgcn_global_load_lds((GV*)g, (LV*)l, 16, 0, 0);
}

// ---------------- convert / prep kernels ----------------

// out[n][k] = bf16(in[k][n]) for 4 weight matrices, z-indexed (one launch)
__global__ void cvt_wT4_kernel(const float* __restrict__ w0, const float* __restrict__ w1,
                               const float* __restrict__ w2, const float* __restrict__ w3,
                               u16* __restrict__ o0, u16* __restrict__ o3) {
  __shared__ float tile[64][65];
  const int z = blockIdx.z;
  const float* in = (z == 0) ? w0 : (z == 1) ? w1 : (z == 2) ? w2 : w3;
  u16* out = (z == 3) ? o3 : o0 + (size_t)z * 768 * 768;
  const int k0 = blockIdx.x * 64, n0 = blockIdx.y * 64;
  const int t = threadIdx.x;
  const int tr = t >> 6, tc = t & 63;
#pragma unroll
  for (int i = 0; i < 16; ++i) {
    int row = i * 4 + tr;
    tile[row][tc] = in[(size_t)(k0 + row) * 768 + n0 + tc];
  }
  __syncthreads();
#pragma unroll
  for (int i = 0; i < 16; ++i) {
    int row = i * 4 + tr;
    out[(size_t)(n0 + row) * 768 + k0 + tc] = f2bf(tile[tc][row]);
  }
}

// bias in bf16 fragment layout: bp[(kb*577 + q)*8 + j] = log2e * bias(q, k=kb*8+j)
__global__ void bias_kernel(const float* __restrict__ table, u16* __restrict__ bp) {
  int idx = blockIdx.x * 256 + threadIdx.x;
  if (idx >= 577 * 76) return;
  int q = idx / 76, kb = idx - q * 76;
  u16 o8[8];
#pragma unroll
  for (int j = 0; j < 8; ++j) {
    int k = kb * 8 + j;
    float v = 0.f;
    if (k <= 576) {
      int id;
      if (q == 0 && k == 0) id = 9;
      else if (q == 0) id = 10;
      else if (k == 0) id = 11;
      else {
        int qy = (q - 1) / 24, qx = (q - 1) % 24;
        int ky = (k - 1) / 24, kx = (k - 1) % 24;
        int ry = qy - ky; ry = ry < -1 ? -1 : (ry > 1 ? 1 : ry);
        int rx = qx - kx; rx = rx < -1 ? -1 : (rx > 1 ? 1 : rx);
        id = (ry + 1) * 3 + (rx + 1);
      }
      v = table[id] * 1.4426950408889634f;
    }
    o8[j] = f2bf(v);
  }
  *(uint4*)(bp + ((size_t)kb * 577 + q) * 8) = *(const uint4*)o8;
}

// bias(q, k=576) * log2e
__global__ void bias576_kernel(const float* __restrict__ table, float* __restrict__ b576) {
  int q = blockIdx.x * 256 + threadIdx.x;
  if (q >= 577) return;
  int id;
  if (q == 0) id = 10;
  else {
    int qy = (q - 1) / 24, qx = (q - 1) % 24;
    int ry = qy - 23; ry = ry < -1 ? -1 : (ry > 1 ? 1 : ry);
    int rx = qx - 23; rx = rx < -1 ? -1 : (rx > 1 ? 1 : rx);
    id = (ry + 1) * 3 + (rx + 1);
  }
  b576[q] = table[id] * 1.4426950408889634f;
}

// ---------------- GEMM (256x256 tile, BK=32, 2-phase dbuf) ----------------
// Round-10 proven structure. MODE 0: A is f32 (x) — conversion FUSED into staging:
// f32 loads issued at iteration top (T14 issue-early), cvt_pk + ds_write after the MFMA
// block (write-late; WAR-safe: buf^1's readers finished before the previous barrier).
// MODE 1: A is bf16, pure global_load_lds staging.

template <int MODE>
__global__ __launch_bounds__(512, 2) void gemm_kernel(
    const void* __restrict__ Av, const u16* __restrict__ BT,
    const int M, const int NBN,
    float* __restrict__ outF, const float* __restrict__ bvec,
    u16* __restrict__ qarr, u16* __restrict__ karr, u16* __restrict__ vTa) {
  constexpr int K = 768;
  __shared__ __align__(16) u16 smem[33792];
  u16* As = smem;           // [2][8192]
  u16* Bs = smem + 16384;   // [2][8192]
  u16* Cs = smem;

  // bijective XCD remap (m204)
  const int nwg = gridDim.x;
  const int q8 = nwg >> 3, r8 = nwg & 7;
  const int xcd = blockIdx.x & 7, jj = blockIdx.x >> 3;
  const int bid = ((xcd < r8) ? xcd * (q8 + 1) : r8 * (q8 + 1) + (xcd - r8) * q8) + jj;

  const int nb = bid % NBN, mb = bid / NBN;
  const int tid = threadIdx.x;
  const int wid = tid >> 6, l = tid & 63;
  const int wrm = wid >> 2, wcn = wid & 3;
  const int l15 = l & 15, l4 = l >> 4;
  const int m0 = mb * 256, n0 = nb * 256;

  floatx4 acc[8][4];
#pragma unroll
  for (int i = 0; i < 8; ++i)
#pragma unroll
    for (int j = 0; j < 4; ++j) acc[i][j] = 0.f;

  const int r1 = tid >> 2;          // 0..127
  const int g1 = (tid & 3) * 8;     // col elem offset
  int ar0 = m0 + r1;       if (ar0 >= M) ar0 = M - 1;
  int ar1 = m0 + r1 + 128; if (ar1 >= M) ar1 = M - 1;
  const u16* pb0 = BT + (size_t)(n0 + r1) * K + g1;
  const u16* pb1 = BT + (size_t)(n0 + r1 + 128) * K + g1;

  auto stageB = [&](int buf, int kt) {
    gload16(pb0 + kt * 32, &Bs[buf * 8192 + tid * 8]);
    gload16(pb1 + kt * 32, &Bs[buf * 8192 + 4096 + tid * 8]);
  };

  auto compute = [&](int cur) {
    short8 af[8], bf[4];
#pragma unroll
    for (int mi = 0; mi < 8; ++mi)
      af[mi] = *(const short8*)&As[cur * 8192 + (wrm * 128 + mi * 16 + l15) * 32 + l4 * 8];
#pragma unroll
    for (int ni = 0; ni < 4; ++ni)
      bf[ni] = *(const short8*)&Bs[cur * 8192 + (wcn * 64 + ni * 16 + l15) * 32 + l4 * 8];
#pragma unroll
    for (int mi = 0; mi < 8; ++mi)
#pragma unroll
      for (int ni = 0; ni < 4; ++ni)
        acc[mi][ni] = MFMA16(af[mi], bf[ni], acc[mi][ni]);
  };

  if constexpr (MODE == 0) {
    const float* pa0 = (const float*)Av + (size_t)ar0 * K + g1;
    const float* pa1 = (const float*)Av + (size_t)ar1 * K + g1;
    auto loadA = [&](int kt, float4& a, float4& b, float4& c, float4& d) {
      const int k0 = kt * 32;
      a = *(const float4*)(pa0 + k0);
      b = *(const float4*)(pa0 + k0 + 4);
      c = *(const float4*)(pa1 + k0);
      d = *(const float4*)(pa1 + k0 + 4);
    };
    auto writeA = [&](int buf, float4 a, float4 b, float4 c, float4 d) {
      uint4 w0, w1;
      w0.x = cvtpk_bf16(a.x, a.y); w0.y = cvtpk_bf16(a.z, a.w);
      w0.z = cvtpk_bf16(b.x, b.y); w0.w = cvtpk_bf16(b.z, b.w);
      w1.x = cvtpk_bf16(c.x, c.y); w1.y = cvtpk_bf16(c.z, c.w);
      w1.z = cvtpk_bf16(d.x, d.y); w1.w = cvtpk_bf16(d.z, d.w);
      *(uint4*)&As[buf * 8192 + tid * 8] = w0;
      *(uint4*)&As[buf * 8192 + 4096 + tid * 8] = w1;
    };
    {
      float4 t0, t1, t2, t3;
      loadA(0, t0, t1, t2, t3);
      stageB(0, 0);
      writeA(0, t0, t1, t2, t3);
    }
    __syncthreads();
    int cur = 0;
    for (int kt = 0; kt < 24; ++kt) {
      float4 u0, u1, u2, u3;
      if (kt + 1 < 24) { loadA(kt + 1, u0, u1, u2, u3); stageB(cur ^ 1, kt + 1); }
      compute(cur);
      if (kt + 1 < 24) writeA(cur ^ 1, u0, u1, u2, u3);
      __syncthreads();
      cur ^= 1;
    }
  } else {
    const u16* pa0 = (const u16*)Av + (size_t)ar0 * K + g1;
    const u16* pa1 = (const u16*)Av + (size_t)ar1 * K + g1;
    auto stageA = [&](int buf, int kt) {
      gload16(pa0 + kt * 32, &As[buf * 8192 + tid * 8]);
      gload16(pa1 + kt * 32, &As[buf * 8192 + 4096 + tid * 8]);
    };
    stageA(0, 0); stageB(0, 0);
    __syncthreads();
    int cur = 0;
    for (int kt = 0; kt < 24; ++kt) {
      if (kt + 1 < 24) { stageA(cur ^ 1, kt + 1); stageB(cur ^ 1, kt + 1); }
      compute(cur);
      __syncthreads();
      cur ^= 1;
    }
  }

  if constexpr (MODE == 0) {
    const int proj = nb / 3;              // 0=q 1=k 2=v (256 cols = 4 heads)
    const int h0 = (nb - proj * 3) * 4;
    const float qs = (proj == 0) ? 0.18033688011112042f : 1.0f;
#pragma unroll
    for (int p = 0; p < 2; ++p) {
      __syncthreads();
      if (wrm == p) {
#pragma unroll
        for (int mi = 0; mi < 8; ++mi)
#pragma unroll
          for (int i = 0; i < 4; ++i) {
            const int rloc = mi * 16 + l4 * 4 + i;
#pragma unroll
            for (int ni = 0; ni < 4; ++ni)
              Cs[rloc * 264 + wcn * 64 + ni * 16 + l15] = f2bf(acc[mi][ni][i] * qs);
          }
      }
      __syncthreads();
      const int r = tid & 127, ch = tid >> 7;   // 128 rows x 4 head-chunks
      const int mrow = m0 + p * 128 + r;
      if (mrow < M) {
        const int bq = mrow / 577, sq = mrow - bq * 577;
        const u16* src = Cs + r * 264 + ch * 64;
        if (proj < 2) {
          u16* dst = (proj == 0) ? qarr : karr;
          u16* base = dst + ((size_t)(bq * 12 + h0 + ch) * 577 + sq) * 64;
#pragma unroll
          for (int j2 = 0; j2 < 8; ++j2)
            *(uint4*)(base + j2 * 8) = *(const uint4*)(src + j2 * 8);
        } else {
          u16* vbase = vTa + ((size_t)(bq * 12 + h0 + ch) * 64) * 608 + sq;
#pragma unroll
          for (int dc = 0; dc < 8; ++dc) {
            const short8 vv = *(const short8*)(src + dc * 8);
#pragma unroll
            for (int jx = 0; jx < 8; ++jx)
              vbase[(size_t)(dc * 8 + jx) * 608] = (u16)vv[jx];
          }
        }
      }
    }
  } else {
#pragma unroll
    for (int mi = 0; mi < 8; ++mi) {
#pragma unroll
      for (int i = 0; i < 4; ++i) {
        const int mrow = m0 + wrm * 128 + mi * 16 + l4 * 4 + i;
        if (mrow >= M) continue;
#pragma unroll
        for (int ni = 0; ni < 4; ++ni) {
          const int ncol = n0 + wcn * 64 + ni * 16 + l15;
          outF[(size_t)mrow * 768 + ncol] = acc[mi][ni][i] + bvec[ncol];
        }
      }
    }
  }
}

// ---------------- fused flash attention (KVBLK=64, LDS-staged K/V, swapped QK^T) ----------
// kv 0..575 in 9 tiles of 64; kv=576 folded into the online-softmax init. 3 blocks/CU.

__global__ __launch_bounds__(256, 3) void attn_kernel(
    const u16* __restrict__ qg, const u16* __restrict__ kg,
    const u16* __restrict__ vT, const u16* __restrict__ bp,
    const float* __restrict__ b576, u16* __restrict__ xa) {
  const int bid = (blockIdx.x & 7) * 240 + (blockIdx.x >> 3);
  const int bh = bid / 5, qblk = bid - bh * 5;
  const int tid = threadIdx.x;
  const int w = tid >> 6, l = tid & 63;
  const int l15 = l & 15, l4 = l >> 4;
  const int qbase = qblk * 128 + w * 32;

  const u16* qh = qg + (size_t)bh * 577 * 64;
  const u16* kh = kg + (size_t)bh * 577 * 64;
  const u16* vh = vT + (size_t)bh * 64 * 608;

  __shared__ u16 Ks[2][64 * 64];
  __shared__ u16 Vs[2][64 * 64];

  // staging constants
  const int sr = tid >> 3;
  const int sb = tid & 7;
  const int ss = ((sr & 7) ^ ((2 * (sr >> 3)) & 7)) & 7;
  const int scol = (sb ^ ss) * 8;

  // read-side constants
  const int sig = ((l15 >> 2) << 3) + (l15 & 3);
  const int s0_ = ((l15 & 3) ^ ((2 * (l15 >> 2)) & 7)) & 7;
  const int s4_ = s0_ ^ 4;
  const int oK00 = sig * 64 + ((l4 ^ s0_) << 3);
  const int oK01 = sig * 64 + (((l4 + 4) ^ s0_) << 3);
  const int oK10 = (sig + 4) * 64 + ((l4 ^ s4_) << 3);
  const int oK11 = (sig + 4) * 64 + (((l4 + 4) ^ s4_) << 3);
  int oV[4][2];
#pragma unroll
  for (int df = 0; df < 4; ++df) {
    const int r = df * 16 + l15;
    const int sv = ((r & 7) ^ ((2 * (r >> 3)) & 7)) & 7;
    oV[df][0] = r * 64 + ((l4 ^ sv) << 3);
    oV[df][1] = r * 64 + (((l4 + 4) ^ sv) << 3);
  }

  short8 qf[2][2];
  int bq[2];
#pragma unroll
  for (int g = 0; g < 2; ++g) {
    int qr = qbase + g * 16 + l15; if (qr > 576) qr = 576;
    bq[g] = qr;
    qf[g][0] = *(const short8*)(qh + qr * 64 + l4 * 8);
    qf[g][1] = *(const short8*)(qh + qr * 64 + 32 + l4 * 8);
  }

  // ---- init with kv = 576 column ----
  float m[2], lsum[2] = {1.f, 1.f};
  {
    const u16* kp = kh + 576 * 64 + l4 * 8;
    const short8 kA = *(const short8*)(kp);
    const short8 kB = *(const short8*)(kp + 32);
#pragma unroll
    for (int g = 0; g < 2; ++g) {
      float acc = 0.f;
#pragma unroll
      for (int j = 0; j < 8; ++j)
        acc += bf2f((u16)qf[g][0][j]) * bf2f((u16)kA[j]) +
               bf2f((u16)qf[g][1][j]) * bf2f((u16)kB[j]);
      acc += __shfl_xor(acc, 16);
      acc += __shfl_xor(acc, 32);
      m[g] = acc + b576[bq[g]];
    }
  }
  floatx4 o[2][4];
#pragma unroll
  for (int df = 0; df < 4; ++df)
#pragma unroll
    for (int i = 0; i < 4; ++i) {
      const float v5 = bf2f(vh[(size_t)(df * 16 + l4 * 4 + i) * 608 + 576]);
      o[0][df][i] = v5; o[1][df][i] = v5;
    }

  // prologue: stage tile 0
  gload16(kh + (size_t)sr * 64 + scol, &Ks[0][sr * 64 + sb * 8]);
  gload16(kh + (size_t)(sr + 32) * 64 + scol, &Ks[0][(sr + 32) * 64 + sb * 8]);
  gload16(vh + (size_t)sr * 608 + scol, &Vs[0][sr * 64 + sb * 8]);
  gload16(vh + (size_t)(sr + 32) * 608 + scol, &Vs[0][(sr + 32) * 64 + sb * 8]);
  __syncthreads();

  for (int t = 0; t < 9; ++t) {
    const int cur = t & 1;
    if (t < 8) {
      const int nk = (t + 1) * 64;
      gload16(kh + (size_t)(nk + sr) * 64 + scol, &Ks[cur ^ 1][sr * 64 + sb * 8]);
      gload16(kh + (size_t)(nk + sr + 32) * 64 + scol, &Ks[cur ^ 1][(sr + 32) * 64 + sb * 8]);
      gload16(vh + (size_t)sr * 608 + nk + scol, &Vs[cur ^ 1][sr * 64 + sb * 8]);
      gload16(vh + (size_t)(sr + 32) * 608 + nk + scol, &Vs[cur ^ 1][(sr + 32) * 64 + sb * 8]);
    }

    const u16* kb_ = &Ks[cur][0];
    const short8 K00 = *(const short8*)(kb_ + oK00);
    const short8 K01 = *(const short8*)(kb_ + oK01);
    const short8 K10 = *(const short8*)(kb_ + oK10);
    const short8 K11 = *(const short8*)(kb_ + oK11);
    const short8 K20 = *(const short8*)(kb_ + oK00 + 32 * 64);
    const short8 K21 = *(const short8*)(kb_ + oK01 + 32 * 64);
    const short8 K30 = *(const short8*)(kb_ + oK10 + 32 * 64);
    const short8 K31 = *(const short8*)(kb_ + oK11 + 32 * 64);

    floatx4 sA0[2], sA1[2], sB0[2], sB1[2];
    __builtin_amdgcn_s_setprio(1);
#pragma unroll
    for (int g = 0; g < 2; ++g) {
      floatx4 a0 = 0.f, a1 = 0.f, b0 = 0.f, b1 = 0.f;
      a0 = MFMA16(K00, qf[g][0], a0); a0 = MFMA16(K01, qf[g][1], a0);
      a1 = MFMA16(K10, qf[g][0], a1); a1 = MFMA16(K11, qf[g][1], a1);
      b0 = MFMA16(K20, qf[g][0], b0); b0 = MFMA16(K21, qf[g][1], b0);
      b1 = MFMA16(K30, qf[g][0], b1); b1 = MFMA16(K31, qf[g][1], b1);
      sA0[g] = a0; sA1[g] = a1; sB0[g] = b0; sB1[g] = b1;
    }
    __builtin_amdgcn_s_setprio(0);

    // bias loads (L2-resident fragment table), consumed right below
    const int kba = t * 8 + l4;
    const uint4 ba0 = *(const uint4*)(bp + ((size_t)kba * 577 + bq[0]) * 8);
    const uint4 bb0 = *(const uint4*)(bp + ((size_t)(kba + 4) * 577 + bq[0]) * 8);
    const uint4 ba1 = *(const uint4*)(bp + ((size_t)kba * 577 + bq[1]) * 8);
    const uint4 bb1 = *(const uint4*)(bp + ((size_t)(kba + 4) * 577 + bq[1]) * 8);

    float v_[2][16];
#pragma unroll
    for (int g = 0; g < 2; ++g) {
      const uint4 ba = (g == 0) ? ba0 : ba1;
      const uint4 bb = (g == 0) ? bb0 : bb1;
      v_[g][0] = sA0[g][0] + bflo(ba.x);  v_[g][1] = sA0[g][1] + bfhi(ba.x);
      v_[g][2] = sA0[g][2] + bflo(ba.y);  v_[g][3] = sA0[g][3] + bfhi(ba.y);
      v_[g][4] = sA1[g][0] + bflo(ba.z);  v_[g][5] = sA1[g][1] + bfhi(ba.z);
      v_[g][6] = sA1[g][2] + bflo(ba.w);  v_[g][7] = sA1[g][3] + bfhi(ba.w);
      v_[g][8]  = sB0[g][0] + bflo(bb.x); v_[g][9]  = sB0[g][1] + bfhi(bb.x);
      v_[g][10] = sB0[g][2] + bflo(bb.y); v_[g][11] = sB0[g][3] + bfhi(bb.y);
      v_[g][12] = sB1[g][0] + bflo(bb.z); v_[g][13] = sB1[g][1] + bfhi(bb.z);
      v_[g][14] = sB1[g][2] + bflo(bb.w); v_[g][15] = sB1[g][3] + bfhi(bb.w);
    }

    // tree max (depth 4)
    float vm[2];
#pragma unroll
    for (int g = 0; g < 2; ++g) {
      float m0_ = fmaxf(v_[g][0], v_[g][1]),  m1_ = fmaxf(v_[g][2], v_[g][3]);
      float m2_ = fmaxf(v_[g][4], v_[g][5]),  m3_ = fmaxf(v_[g][6], v_[g][7]);
      float m4_ = fmaxf(v_[g][8], v_[g][9]),  m5_ = fmaxf(v_[g][10], v_[g][11]);
      float m6_ = fmaxf(v_[g][12], v_[g][13]), m7_ = fmaxf(v_[g][14], v_[g][15]);
      float a = fmaxf(fmaxf(m0_, m1_), fmaxf(m2_, m3_));
      float b = fmaxf(fmaxf(m4_, m5_), fmaxf(m6_, m7_));
      a = fmaxf(a, b);
      a = fmaxf(a, __shfl_xor(a, 16));
      a = fmaxf(a, __shfl_xor(a, 32));
      vm[g] = a;
    }

    if (__any((vm[0] > m[0] + 8.f) || (vm[1] > m[1] + 8.f))) {
      const float mn0 = fmaxf(m[0], vm[0]), mn1 = fmaxf(m[1], vm[1]);
      const float sc0 = exp2hw(m[0] - mn0), sc1 = exp2hw(m[1] - mn1);
      lsum[0] *= sc0; lsum[1] *= sc1;
#pragma unroll
      for (int df = 0; df < 4; ++df) { o[0][df] *= sc0; o[1][df] *= sc1; }
      m[0] = mn0; m[1] = mn1;
    }

    union PU { unsigned u[4]; short8 s; };
    PU pA[2], pB[2];
#pragma unroll
    for (int g = 0; g < 2; ++g) {
#pragma unroll
      for (int j = 0; j < 16; ++j) v_[g][j] = exp2hw(v_[g][j] - m[g]);
      float s0 = (v_[g][0] + v_[g][1]) + (v_[g][2] + v_[g][3]);
      float s1 = (v_[g][4] + v_[g][5]) + (v_[g][6] + v_[g][7]);
      float s2 = (v_[g][8] + v_[g][9]) + (v_[g][10] + v_[g][11]);
      float s3 = (v_[g][12] + v_[g][13]) + (v_[g][14] + v_[g][15]);
      float rs = (s0 + s1) + (s2 + s3);
      rs += __shfl_xor(rs, 16);
      rs += __shfl_xor(rs, 32);
      lsum[g] += rs;
#pragma unroll
      for (int j = 0; j < 4; ++j) {
        pA[g].u[j] = cvtpk_bf16(v_[g][2 * j], v_[g][2 * j + 1]);
        pB[g].u[j] = cvtpk_bf16(v_[g][8 + 2 * j], v_[g][8 + 2 * j + 1]);
      }
    }

    const u16* vb_ = &Vs[cur][0];
    const short8 vA0 = *(const short8*)(vb_ + oV[0][0]);
    const short8 vB0 = *(const short8*)(vb_ + oV[0][1]);
    const short8 vA1 = *(const short8*)(vb_ + oV[1][0]);
    const short8 vB1 = *(const short8*)(vb_ + oV[1][1]);
    const short8 vA2 = *(const short8*)(vb_ + oV[2][0]);
    const short8 vB2 = *(const short8*)(vb_ + oV[2][1]);
    const short8 vA3 = *(const short8*)(vb_ + oV[3][0]);
    const short8 vB3 = *(const short8*)(vb_ + oV[3][1]);

    __builtin_amdgcn_s_setprio(1);
#pragma unroll
    for (int g = 0; g < 2; ++g) {
      o[g][0] = MFMA16(vA0, pA[g].s, o[g][0]); o[g][0] = MFMA16(vB0, pB[g].s, o[g][0]);
      o[g][1] = MFMA16(vA1, pA[g].s, o[g][1]); o[g][1] = MFMA16(vB1, pB[g].s, o[g][1]);
      o[g][2] = MFMA16(vA2, pA[g].s, o[g][2]); o[g][2] = MFMA16(vB2, pB[g].s, o[g][2]);
      o[g][3] = MFMA16(vA3, pA[g].s, o[g][3]); o[g][3] = MFMA16(vB3, pB[g].s, o[g][3]);
    }
    __builtin_amdgcn_s_setprio(0);

    __syncthreads();
  }

  const int b = bh / 12, h = bh - (bh / 12) * 12;
#pragma unroll
  for (int g = 0; g < 2; ++g) {
    const int gq = qbase + g * 16 + l15;
    if (gq < 577) {
      const float inv = 1.f / lsum[g];
      u16* op = xa + ((size_t)(b * 577 + gq)) * 768 + h * 64 + l4 * 4;
#pragma unroll
      for (int d = 0; d < 4; ++d) {
        unsigned w0 = cvtpk_bf16(o[g][d][0] * inv, o[g][d][1] * inv);
        unsigned w1 = cvtpk_bf16(o[g][d][2] * inv, o[g][d][3] * inv);
        *(unsigned*)(op + d * 16) = w0;
        *(unsigned*)(op + d * 16 + 2) = w1;
      }
    }
  }
}

// ---------------- launch ----------------

extern "C" void kernel_launch(void* const* d_in, const int* in_sizes, int n_in,
                              void* d_out, int out_size, void* d_ws, size_t ws_size,
                              hipStream_t stream) {
  const float* x  = (const float*)d_in[0];
  const float* Wq = (const float*)d_in[1];
  const float* Wk = (const float*)d_in[2];
  const float* Wv = (const float*)d_in[3];
  const float* Wo = (const float*)d_in[4];
  const float* bo = (const float*)d_in[5];
  const float* bt = (const float*)d_in[6];
  float* out = (float*)d_out;

  char* ws = (char*)d_ws;
  size_t off = 0;
  auto alloc = [&](size_t bytes) {
    void* p = ws + off;
    off += (bytes + 255) & ~(size_t)255;
    return p;
  };
  u16* xa   = (u16*)alloc((size_t)18464 * 768 * 2);   // attn output (bf16)
  u16* WT   = (u16*)alloc((size_t)2304 * 768 * 2);
  u16* WoT  = (u16*)alloc((size_t)768 * 768 * 2);
  u16* qa   = (u16*)alloc((size_t)384 * 577 * 64 * 2);
  u16* ka   = (u16*)alloc((size_t)384 * 577 * 64 * 2);
  u16* vT   = (u16*)alloc((size_t)384 * 64 * 608 * 2);
  u16* biasPk = (u16*)alloc((size_t)76 * 577 * 8 * 2);
  float* b576 = (float*)alloc((size_t)577 * 4);
  (void)ws_size; (void)in_sizes; (void)n_in; (void)out_size;

  dim3 tg4(12, 12, 4);
  cvt_wT4_kernel<<<tg4, 256, 0, stream>>>(Wq, Wk, Wv, Wo, WT, WoT);
  bias_kernel<<<(577 * 76 + 255) / 256, 256, 0, stream>>>(bt, biasPk);
  bias576_kernel<<<3, 256, 0, stream>>>(bt, b576);

  // QKV projection: A = x (f32, converted in staging); 256x256 tiles -> 73 x 9 blocks
  gemm_kernel<0><<<73 * 9, 512, 0, stream>>>((const void*)x, WT, 18464, 9,
                                             nullptr, nullptr, qa, ka, vT);
  // attention -> xa
  attn_kernel<<<1920, 256, 0, stream>>>(qa, ka, vT, biasPk, b576, xa);
  // output projection: xa x WoT + bo -> out (f32); 73 x 3 blocks
  gemm_kernel<1><<<73 * 3, 512, 0, stream>>>((const void*)xa, WoT, 18464, 3,
                                             out, bo, nullptr, nullptr, nullptr);
}

// Round 13
// 216.591 us; speedup vs baseline: 1.0528x; 1.0528x over previous
//
#include <hip/hip_runtime.h>

typedef unsigned short u16;
typedef short short8 __attribute__((ext_vector_type(8)));
typedef float floatx4 __attribute__((ext_vector_type(4)));

#define MFMA16(a, b, c) __builtin_amdgcn_mfma_f32_16x16x32_bf16((a), (b), (c), 0, 0, 0)

__device__ __forceinline__ u16 f2bf(float f) {
  unsigned u = __builtin_bit_cast(unsigned, f);
  u = (u + 0x7fffu + ((u >> 16) & 1u)) >> 16;
  return (u16)u;
}

__device__ __forceinline__ float bf2f(u16 u) {
  return __builtin_bit_cast(float, ((unsigned)u) << 16);
}

__device__ __forceinline__ float exp2hw(float x) {
  float r; asm("v_exp_f32 %0, %1" : "=v"(r) : "v"(x)); return r;
}

__device__ __forceinline__ unsigned cvtpk_bf16(float lo, float hi) {
  unsigned r;
  asm("v_cvt_pk_bf16_f32 %0, %1, %2" : "=v"(r) : "v"(lo), "v"(hi));
  return r;
}

__device__ __forceinline__ float bflo(unsigned u) {
  return __builtin_bit_cast(float, u << 16);
}
__device__ __forceinline__ float bfhi(unsigned u) {
  return __builtin_bit_cast(float, u & 0xffff0000u);
}

__device__ __forceinline__ void gload16(const void* g, void* l) {
  typedef __attribute__((address_space(1))) const void GV;
  typedef __attribute__((address_space(3))) void LV;
  __builtin_amdgcn_global_load_lds((GV*)g, (LV*)l, 16, 0, 0);
}

// ---------------- convert / prep kernels ----------------

__global__ void cvt_x_kernel(const float* __restrict__ x, u16* __restrict__ xb, int n4) {
  int i = blockIdx.x * 256 + threadIdx.x;
  if (i >= n4) return;
  float4 v = ((const float4*)x)[i];
  ushort4 r; r.x = f2bf(v.x); r.y = f2bf(v.y); r.z = f2bf(v.z); r.w = f2bf(v.w);
  ((ushort4*)xb)[i] = r;
}

// out[n][k] = bf16(in[k][n]) for 4 weight matrices, z-indexed (one launch)
__global__ void cvt_wT4_kernel(const float* __restrict__ w0, const float* __restrict__ w1,
                               const float* __restrict__ w2, const float* __restrict__ w3,
                               u16* __restrict__ o0, u16* __restrict__ o3) {
  __shared__ float tile[64][65];
  const int z = blockIdx.z;
  const float* in = (z == 0) ? w0 : (z == 1) ? w1 : (z == 2) ? w2 : w3;
  u16* out = (z == 3) ? o3 : o0 + (size_t)z * 768 * 768;
  const int k0 = blockIdx.x * 64, n0 = blockIdx.y * 64;
  const int t = threadIdx.x;
  const int tr = t >> 6, tc = t & 63;
#pragma unroll
  for (int i = 0; i < 16; ++i) {
    int row = i * 4 + tr;
    tile[row][tc] = in[(size_t)(k0 + row) * 768 + n0 + tc];
  }
  __syncthreads();
#pragma unroll
  for (int i = 0; i < 16; ++i) {
    int row = i * 4 + tr;
    out[(size_t)(n0 + row) * 768 + k0 + tc] = f2bf(tile[tc][row]);
  }
}

// bias in bf16 fragment layout: bp[(kb*577 + q)*8 + j] = log2e * bias(q, k=kb*8+j)
// tail segment (idx >= 577*76) fills b576[q] = log2e * bias(q, 576)
__global__ void bias_kernel(const float* __restrict__ table, u16* __restrict__ bp,
                            float* __restrict__ b576) {
  int idx = blockIdx.x * 256 + threadIdx.x;
  if (idx >= 577 * 76 + 577) return;
  if (idx >= 577 * 76) {
    int q = idx - 577 * 76;
    int id;
    if (q == 0) id = 10;
    else {
      int qy = (q - 1) / 24, qx = (q - 1) % 24;
      int ry = qy - 23; ry = ry < -1 ? -1 : (ry > 1 ? 1 : ry);
      int rx = qx - 23; rx = rx < -1 ? -1 : (rx > 1 ? 1 : rx);
      id = (ry + 1) * 3 + (rx + 1);
    }
    b576[q] = table[id] * 1.4426950408889634f;
    return;
  }
  int q = idx / 76, kb = idx - q * 76;
  u16 o8[8];
#pragma unroll
  for (int j = 0; j < 8; ++j) {
    int k = kb * 8 + j;
    float v = 0.f;
    if (k <= 576) {
      int id;
      if (q == 0 && k == 0) id = 9;
      else if (q == 0) id = 10;
      else if (k == 0) id = 11;
      else {
        int qy = (q - 1) / 24, qx = (q - 1) % 24;
        int ky = (k - 1) / 24, kx = (k - 1) % 24;
        int ry = qy - ky; ry = ry < -1 ? -1 : (ry > 1 ? 1 : ry);
        int rx = qx - kx; rx = rx < -1 ? -1 : (rx > 1 ? 1 : rx);
        id = (ry + 1) * 3 + (rx + 1);
      }
      v = table[id] * 1.4426950408889634f;
    }
    o8[j] = f2bf(v);
  }
  *(uint4*)(bp + ((size_t)kb * 577 + q) * 8) = *(const uint4*)o8;
}

// ---------------- GEMM (256x256 tile, BK=32, 2-phase dbuf, global_load_lds) ----------------
// Round-10 proven config (structural plateau for this shape; ring/counted-vmcnt variants
// measured negative — rounds 9/11/12). 512 threads = 8 waves (2M x 4N).

template <int MODE>
__global__ __launch_bounds__(512, 2) void gemm_kernel(
    const u16* __restrict__ A, const u16* __restrict__ BT,
    const int M, const int NBN,
    float* __restrict__ outF, const float* __restrict__ bvec,
    u16* __restrict__ qarr, u16* __restrict__ karr, u16* __restrict__ vTa) {
  constexpr int K = 768;
  __shared__ __align__(16) u16 smem[33792];
  u16* As = smem;           // [2][8192]
  u16* Bs = smem + 16384;   // [2][8192]
  u16* Cs = smem;

  // bijective XCD remap (m204)
  const int nwg = gridDim.x;
  const int q8 = nwg >> 3, r8 = nwg & 7;
  const int xcd = blockIdx.x & 7, jj = blockIdx.x >> 3;
  const int bid = ((xcd < r8) ? xcd * (q8 + 1) : r8 * (q8 + 1) + (xcd - r8) * q8) + jj;

  const int nb = bid % NBN, mb = bid / NBN;
  const int tid = threadIdx.x;
  const int wid = tid >> 6, l = tid & 63;
  const int wrm = wid >> 2, wcn = wid & 3;
  const int l15 = l & 15, l4 = l >> 4;
  const int m0 = mb * 256, n0 = nb * 256;

  floatx4 acc[8][4];
#pragma unroll
  for (int i = 0; i < 8; ++i)
#pragma unroll
    for (int j = 0; j < 4; ++j) acc[i][j] = 0.f;

  const int r1 = tid >> 2;          // 0..127
  const int g1 = (tid & 3) * 8;     // col elem offset

  auto stage = [&](int buf, int kt) {
    const int k0 = kt * 32 + g1;
    int ar0 = m0 + r1;       if (ar0 >= M) ar0 = M - 1;
    int ar1 = m0 + r1 + 128; if (ar1 >= M) ar1 = M - 1;
    gload16(A + (size_t)ar0 * K + k0, &As[buf * 8192 + tid * 8]);
    gload16(A + (size_t)ar1 * K + k0, &As[buf * 8192 + 4096 + tid * 8]);
    gload16(BT + (size_t)(n0 + r1) * K + k0, &Bs[buf * 8192 + tid * 8]);
    gload16(BT + (size_t)(n0 + r1 + 128) * K + k0, &Bs[buf * 8192 + 4096 + tid * 8]);
  };

  stage(0, 0);
  __syncthreads();
  int cur = 0;
  for (int kt = 0; kt < 24; ++kt) {
    if (kt + 1 < 24) stage(cur ^ 1, kt + 1);
    short8 af[8], bf[4];
#pragma unroll
    for (int mi = 0; mi < 8; ++mi)
      af[mi] = *(const short8*)&As[cur * 8192 + (wrm * 128 + mi * 16 + l15) * 32 + l4 * 8];
#pragma unroll
    for (int ni = 0; ni < 4; ++ni)
      bf[ni] = *(const short8*)&Bs[cur * 8192 + (wcn * 64 + ni * 16 + l15) * 32 + l4 * 8];
#pragma unroll
    for (int mi = 0; mi < 8; ++mi)
#pragma unroll
      for (int ni = 0; ni < 4; ++ni)
        acc[mi][ni] = MFMA16(af[mi], bf[ni], acc[mi][ni]);
    __syncthreads();
    cur ^= 1;
  }

  if constexpr (MODE == 0) {
    const int proj = nb / 3;              // 0=q 1=k 2=v (256 cols = 4 heads)
    const int h0 = (nb - proj * 3) * 4;
    const float qs = (proj == 0) ? 0.18033688011112042f : 1.0f;
#pragma unroll
    for (int p = 0; p < 2; ++p) {
      __syncthreads();
      if (wrm == p) {
#pragma unroll
        for (int mi = 0; mi < 8; ++mi)
#pragma unroll
          for (int i = 0; i < 4; ++i) {
            const int rloc = mi * 16 + l4 * 4 + i;
#pragma unroll
            for (int ni = 0; ni < 4; ++ni)
              Cs[rloc * 264 + wcn * 64 + ni * 16 + l15] = f2bf(acc[mi][ni][i] * qs);
          }
      }
      __syncthreads();
      const int r = tid & 127, ch = tid >> 7;   // 128 rows x 4 head-chunks
      const int mrow = m0 + p * 128 + r;
      if (mrow < M) {
        const int bq = mrow / 577, sq = mrow - bq * 577;
        const u16* src = Cs + r * 264 + ch * 64;
        if (proj < 2) {
          u16* dst = (proj == 0) ? qarr : karr;
          u16* base = dst + ((size_t)(bq * 12 + h0 + ch) * 577 + sq) * 64;
#pragma unroll
          for (int j2 = 0; j2 < 8; ++j2)
            *(uint4*)(base + j2 * 8) = *(const uint4*)(src + j2 * 8);
        } else {
          u16* vbase = vTa + ((size_t)(bq * 12 + h0 + ch) * 64) * 608 + sq;
#pragma unroll
          for (int dc = 0; dc < 8; ++dc) {
            const short8 vv = *(const short8*)(src + dc * 8);
#pragma unroll
            for (int jx = 0; jx < 8; ++jx)
              vbase[(size_t)(dc * 8 + jx) * 608] = (u16)vv[jx];
          }
        }
      }
    }
  } else {
#pragma unroll
    for (int mi = 0; mi < 8; ++mi) {
#pragma unroll
      for (int i = 0; i < 4; ++i) {
        const int mrow = m0 + wrm * 128 + mi * 16 + l4 * 4 + i;
        if (mrow >= M) continue;
#pragma unroll
        for (int ni = 0; ni < 4; ++ni) {
          const int ncol = n0 + wcn * 64 + ni * 16 + l15;
          outF[(size_t)mrow * 768 + ncol] = acc[mi][ni][i] + bvec[ncol];
        }
      }
    }
  }
}

// ---------------- fused flash attention (KVBLK=64, LDS-staged K/V, swapped QK^T) ----------
// kv 0..575 in 9 tiles of 64; kv=576 folded into the online-softmax init. 3 blocks/CU.

__global__ __launch_bounds__(256, 3) void attn_kernel(
    const u16* __restrict__ qg, const u16* __restrict__ kg,
    const u16* __restrict__ vT, const u16* __restrict__ bp,
    const float* __restrict__ b576, u16* __restrict__ xa) {
  const int bid = (blockIdx.x & 7) * 240 + (blockIdx.x >> 3);
  const int bh = bid / 5, qblk = bid - bh * 5;
  const int tid = threadIdx.x;
  const int w = tid >> 6, l = tid & 63;
  const int l15 = l & 15, l4 = l >> 4;
  const int qbase = qblk * 128 + w * 32;

  const u16* qh = qg + (size_t)bh * 577 * 64;
  const u16* kh = kg + (size_t)bh * 577 * 64;
  const u16* vh = vT + (size_t)bh * 64 * 608;

  __shared__ u16 Ks[2][64 * 64];
  __shared__ u16 Vs[2][64 * 64];

  // staging constants
  const int sr = tid >> 3;
  const int sb = tid & 7;
  const int ss = ((sr & 7) ^ ((2 * (sr >> 3)) & 7)) & 7;
  const int scol = (sb ^ ss) * 8;

  // read-side constants
  const int sig = ((l15 >> 2) << 3) + (l15 & 3);
  const int s0_ = ((l15 & 3) ^ ((2 * (l15 >> 2)) & 7)) & 7;
  const int s4_ = s0_ ^ 4;
  const int oK00 = sig * 64 + ((l4 ^ s0_) << 3);
  const int oK01 = sig * 64 + (((l4 + 4) ^ s0_) << 3);
  const int oK10 = (sig + 4) * 64 + ((l4 ^ s4_) << 3);
  const int oK11 = (sig + 4) * 64 + (((l4 + 4) ^ s4_) << 3);
  int oV[4][2];
#pragma unroll
  for (int df = 0; df < 4; ++df) {
    const int r = df * 16 + l15;
    const int sv = ((r & 7) ^ ((2 * (r >> 3)) & 7)) & 7;
    oV[df][0] = r * 64 + ((l4 ^ sv) << 3);
    oV[df][1] = r * 64 + (((l4 + 4) ^ sv) << 3);
  }

  short8 qf[2][2];
  int bq[2];
#pragma unroll
  for (int g = 0; g < 2; ++g) {
    int qr = qbase + g * 16 + l15; if (qr > 576) qr = 576;
    bq[g] = qr;
    qf[g][0] = *(const short8*)(qh + qr * 64 + l4 * 8);
    qf[g][1] = *(const short8*)(qh + qr * 64 + 32 + l4 * 8);
  }

  // ---- init with kv = 576 column ----
  float m[2], lsum[2] = {1.f, 1.f};
  {
    const u16* kp = kh + 576 * 64 + l4 * 8;
    const short8 kA = *(const short8*)(kp);
    const short8 kB = *(const short8*)(kp + 32);
#pragma unroll
    for (int g = 0; g < 2; ++g) {
      float acc = 0.f;
#pragma unroll
      for (int j = 0; j < 8; ++j)
        acc += bf2f((u16)qf[g][0][j]) * bf2f((u16)kA[j]) +
               bf2f((u16)qf[g][1][j]) * bf2f((u16)kB[j]);
      acc += __shfl_xor(acc, 16);
      acc += __shfl_xor(acc, 32);
      m[g] = acc + b576[bq[g]];
    }
  }
  floatx4 o[2][4];
#pragma unroll
  for (int df = 0; df < 4; ++df)
#pragma unroll
    for (int i = 0; i < 4; ++i) {
      const float v5 = bf2f(vh[(size_t)(df * 16 + l4 * 4 + i) * 608 + 576]);
      o[0][df][i] = v5; o[1][df][i] = v5;
    }

  // prologue: stage tile 0
  gload16(kh + (size_t)sr * 64 + scol, &Ks[0][sr * 64 + sb * 8]);
  gload16(kh + (size_t)(sr + 32) * 64 + scol, &Ks[0][(sr + 32) * 64 + sb * 8]);
  gload16(vh + (size_t)sr * 608 + scol, &Vs[0][sr * 64 + sb * 8]);
  gload16(vh + (size_t)(sr + 32) * 608 + scol, &Vs[0][(sr + 32) * 64 + sb * 8]);
  __syncthreads();

  for (int t = 0; t < 9; ++t) {
    const int cur = t & 1;
    if (t < 8) {
      const int nk = (t + 1) * 64;
      gload16(kh + (size_t)(nk + sr) * 64 + scol, &Ks[cur ^ 1][sr * 64 + sb * 8]);
      gload16(kh + (size_t)(nk + sr + 32) * 64 + scol, &Ks[cur ^ 1][(sr + 32) * 64 + sb * 8]);
      gload16(vh + (size_t)sr * 608 + nk + scol, &Vs[cur ^ 1][sr * 64 + sb * 8]);
      gload16(vh + (size_t)(sr + 32) * 608 + nk + scol, &Vs[cur ^ 1][(sr + 32) * 64 + sb * 8]);
    }

    const u16* kb_ = &Ks[cur][0];
    const short8 K00 = *(const short8*)(kb_ + oK00);
    const short8 K01 = *(const short8*)(kb_ + oK01);
    const short8 K10 = *(const short8*)(kb_ + oK10);
    const short8 K11 = *(const short8*)(kb_ + oK11);
    const short8 K20 = *(const short8*)(kb_ + oK00 + 32 * 64);
    const short8 K21 = *(const short8*)(kb_ + oK01 + 32 * 64);
    const short8 K30 = *(const short8*)(kb_ + oK10 + 32 * 64);
    const short8 K31 = *(const short8*)(kb_ + oK11 + 32 * 64);

    floatx4 sA0[2], sA1[2], sB0[2], sB1[2];
    __builtin_amdgcn_s_setprio(1);
#pragma unroll
    for (int g = 0; g < 2; ++g) {
      floatx4 a0 = 0.f, a1 = 0.f, b0 = 0.f, b1 = 0.f;
      a0 = MFMA16(K00, qf[g][0], a0); a0 = MFMA16(K01, qf[g][1], a0);
      a1 = MFMA16(K10, qf[g][0], a1); a1 = MFMA16(K11, qf[g][1], a1);
      b0 = MFMA16(K20, qf[g][0], b0); b0 = MFMA16(K21, qf[g][1], b0);
      b1 = MFMA16(K30, qf[g][0], b1); b1 = MFMA16(K31, qf[g][1], b1);
      sA0[g] = a0; sA1[g] = a1; sB0[g] = b0; sB1[g] = b1;
    }
    __builtin_amdgcn_s_setprio(0);

    // bias loads (L2-resident fragment table), consumed right below
    const int kba = t * 8 + l4;
    const uint4 ba0 = *(const uint4*)(bp + ((size_t)kba * 577 + bq[0]) * 8);
    const uint4 bb0 = *(const uint4*)(bp + ((size_t)(kba + 4) * 577 + bq[0]) * 8);
    const uint4 ba1 = *(const uint4*)(bp + ((size_t)kba * 577 + bq[1]) * 8);
    const uint4 bb1 = *(const uint4*)(bp + ((size_t)(kba + 4) * 577 + bq[1]) * 8);

    float v_[2][16];
#pragma unroll
    for (int g = 0; g < 2; ++g) {
      const uint4 ba = (g == 0) ? ba0 : ba1;
      const uint4 bb = (g == 0) ? bb0 : bb1;
      v_[g][0] = sA0[g][0] + bflo(ba.x);  v_[g][1] = sA0[g][1] + bfhi(ba.x);
      v_[g][2] = sA0[g][2] + bflo(ba.y);  v_[g][3] = sA0[g][3] + bfhi(ba.y);
      v_[g][4] = sA1[g][0] + bflo(ba.z);  v_[g][5] = sA1[g][1] + bfhi(ba.z);
      v_[g][6] = sA1[g][2] + bflo(ba.w);  v_[g][7] = sA1[g][3] + bfhi(ba.w);
      v_[g][8]  = sB0[g][0] + bflo(bb.x); v_[g][9]  = sB0[g][1] + bfhi(bb.x);
      v_[g][10] = sB0[g][2] + bflo(bb.y); v_[g][11] = sB0[g][3] + bfhi(bb.y);
      v_[g][12] = sB1[g][0] + bflo(bb.z); v_[g][13] = sB1[g][1] + bfhi(bb.z);
      v_[g][14] = sB1[g][2] + bflo(bb.w); v_[g][15] = sB1[g][3] + bfhi(bb.w);
    }

    // tree max (depth 4)
    float vm[2];
#pragma unroll
    for (int g = 0; g < 2; ++g) {
      float m0_ = fmaxf(v_[g][0], v_[g][1]),  m1_ = fmaxf(v_[g][2], v_[g][3]);
      float m2_ = fmaxf(v_[g][4], v_[g][5]),  m3_ = fmaxf(v_[g][6], v_[g][7]);
      float m4_ = fmaxf(v_[g][8], v_[g][9]),  m5_ = fmaxf(v_[g][10], v_[g][11]);
      float m6_ = fmaxf(v_[g][12], v_[g][13]), m7_ = fmaxf(v_[g][14], v_[g][15]);
      float a = fmaxf(fmaxf(m0_, m1_), fmaxf(m2_, m3_));
      float b = fmaxf(fmaxf(m4_, m5_), fmaxf(m6_, m7_));
      a = fmaxf(a, b);
      a = fmaxf(a, __shfl_xor(a, 16));
      a = fmaxf(a, __shfl_xor(a, 32));
      vm[g] = a;
    }

    if (__any((vm[0] > m[0] + 8.f) || (vm[1] > m[1] + 8.f))) {
      const float mn0 = fmaxf(m[0], vm[0]), mn1 = fmaxf(m[1], vm[1]);
      const float sc0 = exp2hw(m[0] - mn0), sc1 = exp2hw(m[1] - mn1);
      lsum[0] *= sc0; lsum[1] *= sc1;
#pragma unroll
      for (int df = 0; df < 4; ++df) { o[0][df] *= sc0; o[1][df] *= sc1; }
      m[0] = mn0; m[1] = mn1;
    }

    union PU { unsigned u[4]; short8 s; };
    PU pA[2], pB[2];
#pragma unroll
    for (int g = 0; g < 2; ++g) {
#pragma unroll
      for (int j = 0; j < 16; ++j) v_[g][j] = exp2hw(v_[g][j] - m[g]);
      float s0 = (v_[g][0] + v_[g][1]) + (v_[g][2] + v_[g][3]);
      float s1 = (v_[g][4] + v_[g][5]) + (v_[g][6] + v_[g][7]);
      float s2 = (v_[g][8] + v_[g][9]) + (v_[g][10] + v_[g][11]);
      float s3 = (v_[g][12] + v_[g][13]) + (v_[g][14] + v_[g][15]);
      float rs = (s0 + s1) + (s2 + s3);
      rs += __shfl_xor(rs, 16);
      rs += __shfl_xor(rs, 32);
      lsum[g] += rs;
#pragma unroll
      for (int j = 0; j < 4; ++j) {
        pA[g].u[j] = cvtpk_bf16(v_[g][2 * j], v_[g][2 * j + 1]);
        pB[g].u[j] = cvtpk_bf16(v_[g][8 + 2 * j], v_[g][8 + 2 * j + 1]);
      }
    }

    const u16* vb_ = &Vs[cur][0];
    const short8 vA0 = *(const short8*)(vb_ + oV[0][0]);
    const short8 vB0 = *(const short8*)(vb_ + oV[0][1]);
    const short8 vA1 = *(const short8*)(vb_ + oV[1][0]);
    const short8 vB1 = *(const short8*)(vb_ + oV[1][1]);
    const short8 vA2 = *(const short8*)(vb_ + oV[2][0]);
    const short8 vB2 = *(const short8*)(vb_ + oV[2][1]);
    const short8 vA3 = *(const short8*)(vb_ + oV[3][0]);
    const short8 vB3 = *(const short8*)(vb_ + oV[3][1]);

    __builtin_amdgcn_s_setprio(1);
#pragma unroll
    for (int g = 0; g < 2; ++g) {
      o[g][0] = MFMA16(vA0, pA[g].s, o[g][0]); o[g][0] = MFMA16(vB0, pB[g].s, o[g][0]);
      o[g][1] = MFMA16(vA1, pA[g].s, o[g][1]); o[g][1] = MFMA16(vB1, pB[g].s, o[g][1]);
      o[g][2] = MFMA16(vA2, pA[g].s, o[g][2]); o[g][2] = MFMA16(vB2, pB[g].s, o[g][2]);
      o[g][3] = MFMA16(vA3, pA[g].s, o[g][3]); o[g][3] = MFMA16(vB3, pB[g].s, o[g][3]);
    }
    __builtin_amdgcn_s_setprio(0);

    __syncthreads();
  }

  const int b = bh / 12, h = bh - (bh / 12) * 12;
#pragma unroll
  for (int g = 0; g < 2; ++g) {
    const int gq = qbase + g * 16 + l15;
    if (gq < 577) {
      const float inv = 1.f / lsum[g];
      u16* op = xa + ((size_t)(b * 577 + gq)) * 768 + h * 64 + l4 * 4;
#pragma unroll
      for (int d = 0; d < 4; ++d) {
        unsigned w0 = cvtpk_bf16(o[g][d][0] * inv, o[g][d][1] * inv);
        unsigned w1 = cvtpk_bf16(o[g][d][2] * inv, o[g][d][3] * inv);
        *(unsigned*)(op + d * 16) = w0;
        *(unsigned*)(op + d * 16 + 2) = w1;
      }
    }
  }
}

// ---------------- launch ----------------

extern "C" void kernel_launch(void* const* d_in, const int* in_sizes, int n_in,
                              void* d_out, int out_size, void* d_ws, size_t ws_size,
                              hipStream_t stream) {
  const float* x  = (const float*)d_in[0];
  const float* Wq = (const float*)d_in[1];
  const float* Wk = (const float*)d_in[2];
  const float* Wv = (const float*)d_in[3];
  const float* Wo = (const float*)d_in[4];
  const float* bo = (const float*)d_in[5];
  const float* bt = (const float*)d_in[6];
  float* out = (float*)d_out;

  char* ws = (char*)d_ws;
  size_t off = 0;
  auto alloc = [&](size_t bytes) {
    void* p = ws + off;
    off += (bytes + 255) & ~(size_t)255;
    return p;
  };
  u16* xb   = (u16*)alloc((size_t)18464 * 768 * 2);   // reused as xa after GEMM0
  u16* WT   = (u16*)alloc((size_t)2304 * 768 * 2);
  u16* WoT  = (u16*)alloc((size_t)768 * 768 * 2);
  u16* qa   = (u16*)alloc((size_t)384 * 577 * 64 * 2);
  u16* ka   = (u16*)alloc((size_t)384 * 577 * 64 * 2);
  u16* vT   = (u16*)alloc((size_t)384 * 64 * 608 * 2);
  u16* biasPk = (u16*)alloc((size_t)76 * 577 * 8 * 2);
  float* b576 = (float*)alloc((size_t)577 * 4);
  (void)ws_size; (void)in_sizes; (void)n_in; (void)out_size;

  cvt_x_kernel<<<(18464 * 768 / 4 + 255) / 256, 256, 0, stream>>>(x, xb, 18464 * 768 / 4);
  dim3 tg4(12, 12, 4);
  cvt_wT4_kernel<<<tg4, 256, 0, stream>>>(Wq, Wk, Wv, Wo, WT, WoT);
  bias_kernel<<<(577 * 76 + 577 + 255) / 256, 256, 0, stream>>>(bt, biasPk, b576);

  // QKV projection: [18464][768] x [768][2304]; 256x256 tiles -> 73 x 9 blocks
  gemm_kernel<0><<<73 * 9, 512, 0, stream>>>(xb, WT, 18464, 9,
                                             nullptr, nullptr, qa, ka, vT);
  // attention -> xa (reuse xb region)
  attn_kernel<<<1920, 256, 0, stream>>>(qa, ka, vT, biasPk, b576, xb);
  // output projection: xa x WoT + bo -> out (f32); 73 x 3 blocks
  gemm_kernel<1><<<73 * 3, 512, 0, stream>>>(xb, WoT, 18464, 3,
                                             out, bo, nullptr, nullptr, nullptr);
}

// Round 14
// 215.016 us; speedup vs baseline: 1.0605x; 1.0073x over previous
//
#include <hip/hip_runtime.h>

typedef unsigned short u16;
typedef short short8 __attribute__((ext_vector_type(8)));
typedef float floatx4 __attribute__((ext_vector_type(4)));

#define MFMA16(a, b, c) __builtin_amdgcn_mfma_f32_16x16x32_bf16((a), (b), (c), 0, 0, 0)

__device__ __forceinline__ u16 f2bf(float f) {
  unsigned u = __builtin_bit_cast(unsigned, f);
  u = (u + 0x7fffu + ((u >> 16) & 1u)) >> 16;
  return (u16)u;
}

__device__ __forceinline__ float bf2f(u16 u) {
  return __builtin_bit_cast(float, ((unsigned)u) << 16);
}

__device__ __forceinline__ float exp2hw(float x) {
  float r; asm("v_exp_f32 %0, %1" : "=v"(r) : "v"(x)); return r;
}

__device__ __forceinline__ unsigned cvtpk_bf16(float lo, float hi) {
  unsigned r;
  asm("v_cvt_pk_bf16_f32 %0, %1, %2" : "=v"(r) : "v"(lo), "v"(hi));
  return r;
}

__device__ __forceinline__ float bflo(unsigned u) {
  return __builtin_bit_cast(float, u << 16);
}
__device__ __forceinline__ float bfhi(unsigned u) {
  return __builtin_bit_cast(float, u & 0xffff0000u);
}

__device__ __forceinline__ void gload16(const void* g, void* l) {
  typedef __attribute__((address_space(1))) const void GV;
  typedef __attribute__((address_space(3))) void LV;
  __builtin_amdgcn_global_load_lds((GV*)g, (LV*)l, 16, 0, 0);
}

// ---------------- convert / prep kernels ----------------

__global__ void cvt_x_kernel(const float* __restrict__ x, u16* __restrict__ xb, int n4) {
  int i = blockIdx.x * 256 + threadIdx.x;
  if (i >= n4) return;
  float4 v = ((const float4*)x)[i];
  ushort4 r; r.x = f2bf(v.x); r.y = f2bf(v.y); r.z = f2bf(v.z); r.w = f2bf(v.w);
  ((ushort4*)xb)[i] = r;
}

// out[n][k] = bf16(in[k][n]) for 4 weight matrices, z-indexed (one launch)
__global__ void cvt_wT4_kernel(const float* __restrict__ w0, const float* __restrict__ w1,
                               const float* __restrict__ w2, const float* __restrict__ w3,
                               u16* __restrict__ o0, u16* __restrict__ o3) {
  __shared__ float tile[64][65];
  const int z = blockIdx.z;
  const float* in = (z == 0) ? w0 : (z == 1) ? w1 : (z == 2) ? w2 : w3;
  u16* out = (z == 3) ? o3 : o0 + (size_t)z * 768 * 768;
  const int k0 = blockIdx.x * 64, n0 = blockIdx.y * 64;
  const int t = threadIdx.x;
  const int tr = t >> 6, tc = t & 63;
#pragma unroll
  for (int i = 0; i < 16; ++i) {
    int row = i * 4 + tr;
    tile[row][tc] = in[(size_t)(k0 + row) * 768 + n0 + tc];
  }
  __syncthreads();
#pragma unroll
  for (int i = 0; i < 16; ++i) {
    int row = i * 4 + tr;
    out[(size_t)(n0 + row) * 768 + k0 + tc] = f2bf(tile[tc][row]);
  }
}

// bias in bf16 fragment layout: bp[(kb*577 + q)*8 + j] = log2e * bias(q, k=kb*8+j)
// tail segment (idx >= 577*76) fills b576[q] = log2e * bias(q, 576)
__global__ void bias_kernel(const float* __restrict__ table, u16* __restrict__ bp,
                            float* __restrict__ b576) {
  int idx = blockIdx.x * 256 + threadIdx.x;
  if (idx >= 577 * 76 + 577) return;
  if (idx >= 577 * 76) {
    int q = idx - 577 * 76;
    int id;
    if (q == 0) id = 10;
    else {
      int qy = (q - 1) / 24, qx = (q - 1) % 24;
      int ry = qy - 23; ry = ry < -1 ? -1 : (ry > 1 ? 1 : ry);
      int rx = qx - 23; rx = rx < -1 ? -1 : (rx > 1 ? 1 : rx);
      id = (ry + 1) * 3 + (rx + 1);
    }
    b576[q] = table[id] * 1.4426950408889634f;
    return;
  }
  int q = idx / 76, kb = idx - q * 76;
  u16 o8[8];
#pragma unroll
  for (int j = 0; j < 8; ++j) {
    int k = kb * 8 + j;
    float v = 0.f;
    if (k <= 576) {
      int id;
      if (q == 0 && k == 0) id = 9;
      else if (q == 0) id = 10;
      else if (k == 0) id = 11;
      else {
        int qy = (q - 1) / 24, qx = (q - 1) % 24;
        int ky = (k - 1) / 24, kx = (k - 1) % 24;
        int ry = qy - ky; ry = ry < -1 ? -1 : (ry > 1 ? 1 : ry);
        int rx = qx - kx; rx = rx < -1 ? -1 : (rx > 1 ? 1 : rx);
        id = (ry + 1) * 3 + (rx + 1);
      }
      v = table[id] * 1.4426950408889634f;
    }
    o8[j] = f2bf(v);
  }
  *(uint4*)(bp + ((size_t)kb * 577 + q) * 8) = *(const uint4*)o8;
}

// ---------------- GEMM (256x256 tile, BK=32, 2-phase dbuf, global_load_lds) ----------------
// Round-10 proven config (structural plateau for this shape; ring/counted-vmcnt variants
// measured negative — rounds 9/11/12). 512 threads = 8 waves (2M x 4N).

template <int MODE>
__global__ __launch_bounds__(512, 2) void gemm_kernel(
    const u16* __restrict__ A, const u16* __restrict__ BT,
    const int M, const int NBN,
    float* __restrict__ outF, const float* __restrict__ bvec,
    u16* __restrict__ qarr, u16* __restrict__ karr, u16* __restrict__ vTa) {
  constexpr int K = 768;
  __shared__ __align__(16) u16 smem[33792];
  u16* As = smem;           // [2][8192]
  u16* Bs = smem + 16384;   // [2][8192]
  u16* Cs = smem;

  // bijective XCD remap (m204)
  const int nwg = gridDim.x;
  const int q8 = nwg >> 3, r8 = nwg & 7;
  const int xcd = blockIdx.x & 7, jj = blockIdx.x >> 3;
  const int bid = ((xcd < r8) ? xcd * (q8 + 1) : r8 * (q8 + 1) + (xcd - r8) * q8) + jj;

  const int nb = bid % NBN, mb = bid / NBN;
  const int tid = threadIdx.x;
  const int wid = tid >> 6, l = tid & 63;
  const int wrm = wid >> 2, wcn = wid & 3;
  const int l15 = l & 15, l4 = l >> 4;
  const int m0 = mb * 256, n0 = nb * 256;

  floatx4 acc[8][4];
#pragma unroll
  for (int i = 0; i < 8; ++i)
#pragma unroll
    for (int j = 0; j < 4; ++j) acc[i][j] = 0.f;

  const int r1 = tid >> 2;          // 0..127
  const int g1 = (tid & 3) * 8;     // col elem offset

  auto stage = [&](int buf, int kt) {
    const int k0 = kt * 32 + g1;
    int ar0 = m0 + r1;       if (ar0 >= M) ar0 = M - 1;
    int ar1 = m0 + r1 + 128; if (ar1 >= M) ar1 = M - 1;
    gload16(A + (size_t)ar0 * K + k0, &As[buf * 8192 + tid * 8]);
    gload16(A + (size_t)ar1 * K + k0, &As[buf * 8192 + 4096 + tid * 8]);
    gload16(BT + (size_t)(n0 + r1) * K + k0, &Bs[buf * 8192 + tid * 8]);
    gload16(BT + (size_t)(n0 + r1 + 128) * K + k0, &Bs[buf * 8192 + 4096 + tid * 8]);
  };

  stage(0, 0);
  __syncthreads();
  int cur = 0;
  for (int kt = 0; kt < 24; ++kt) {
    if (kt + 1 < 24) stage(cur ^ 1, kt + 1);
    short8 af[8], bf[4];
#pragma unroll
    for (int mi = 0; mi < 8; ++mi)
      af[mi] = *(const short8*)&As[cur * 8192 + (wrm * 128 + mi * 16 + l15) * 32 + l4 * 8];
#pragma unroll
    for (int ni = 0; ni < 4; ++ni)
      bf[ni] = *(const short8*)&Bs[cur * 8192 + (wcn * 64 + ni * 16 + l15) * 32 + l4 * 8];
#pragma unroll
    for (int mi = 0; mi < 8; ++mi)
#pragma unroll
      for (int ni = 0; ni < 4; ++ni)
        acc[mi][ni] = MFMA16(af[mi], bf[ni], acc[mi][ni]);
    __syncthreads();
    cur ^= 1;
  }

  if constexpr (MODE == 0) {
    const int proj = nb / 3;              // 0=q 1=k 2=v (256 cols = 4 heads)
    const int h0 = (nb - proj * 3) * 4;
    const float qs = (proj == 0) ? 0.18033688011112042f : 1.0f;
#pragma unroll
    for (int p = 0; p < 2; ++p) {
      __syncthreads();
      if (wrm == p) {
#pragma unroll
        for (int mi = 0; mi < 8; ++mi)
#pragma unroll
          for (int i = 0; i < 4; ++i) {
            const int rloc = mi * 16 + l4 * 4 + i;
#pragma unroll
            for (int ni = 0; ni < 4; ++ni)
              Cs[rloc * 264 + wcn * 64 + ni * 16 + l15] = f2bf(acc[mi][ni][i] * qs);
          }
      }
      __syncthreads();
      const int r = tid & 127, ch = tid >> 7;   // 128 rows x 4 head-chunks
      const int mrow = m0 + p * 128 + r;
      if (mrow < M) {
        const int bq = mrow / 577, sq = mrow - bq * 577;
        const u16* src = Cs + r * 264 + ch * 64;
        if (proj < 2) {
          u16* dst = (proj == 0) ? qarr : karr;
          u16* base = dst + ((size_t)(bq * 12 + h0 + ch) * 577 + sq) * 64;
#pragma unroll
          for (int j2 = 0; j2 < 8; ++j2)
            *(uint4*)(base + j2 * 8) = *(const uint4*)(src + j2 * 8);
        } else {
          u16* vbase = vTa + ((size_t)(bq * 12 + h0 + ch) * 64) * 608 + sq;
#pragma unroll
          for (int dc = 0; dc < 8; ++dc) {
            const short8 vv = *(const short8*)(src + dc * 8);
#pragma unroll
            for (int jx = 0; jx < 8; ++jx)
              vbase[(size_t)(dc * 8 + jx) * 608] = (u16)vv[jx];
          }
        }
      }
    }
  } else {
#pragma unroll
    for (int mi = 0; mi < 8; ++mi) {
#pragma unroll
      for (int i = 0; i < 4; ++i) {
        const int mrow = m0 + wrm * 128 + mi * 16 + l4 * 4 + i;
        if (mrow >= M) continue;
#pragma unroll
        for (int ni = 0; ni < 4; ++ni) {
          const int ncol = n0 + wcn * 64 + ni * 16 + l15;
          outF[(size_t)mrow * 768 + ncol] = acc[mi][ni][i] + bvec[ncol];
        }
      }
    }
  }
}

// ---------------- fused flash attention (KVBLK=64, LDS-staged K/V, swapped QK^T) ----------
// kv 0..575 in 9 tiles of 64; kv=576 folded into the online-softmax init. 3 blocks/CU.
// Bias loads issued at LOOP TOP (with the staging gloads) so the K-ds_read + QK-MFMA
// shadow covers their L2 latency; consumed after the MFMA cluster.

__global__ __launch_bounds__(256, 3) void attn_kernel(
    const u16* __restrict__ qg, const u16* __restrict__ kg,
    const u16* __restrict__ vT, const u16* __restrict__ bp,
    const float* __restrict__ b576, u16* __restrict__ xa) {
  const int bid = (blockIdx.x & 7) * 240 + (blockIdx.x >> 3);
  const int bh = bid / 5, qblk = bid - bh * 5;
  const int tid = threadIdx.x;
  const int w = tid >> 6, l = tid & 63;
  const int l15 = l & 15, l4 = l >> 4;
  const int qbase = qblk * 128 + w * 32;

  const u16* qh = qg + (size_t)bh * 577 * 64;
  const u16* kh = kg + (size_t)bh * 577 * 64;
  const u16* vh = vT + (size_t)bh * 64 * 608;

  __shared__ u16 Ks[2][64 * 64];
  __shared__ u16 Vs[2][64 * 64];

  // staging constants
  const int sr = tid >> 3;
  const int sb = tid & 7;
  const int ss = ((sr & 7) ^ ((2 * (sr >> 3)) & 7)) & 7;
  const int scol = (sb ^ ss) * 8;

  // read-side constants
  const int sig = ((l15 >> 2) << 3) + (l15 & 3);
  const int s0_ = ((l15 & 3) ^ ((2 * (l15 >> 2)) & 7)) & 7;
  const int s4_ = s0_ ^ 4;
  const int oK00 = sig * 64 + ((l4 ^ s0_) << 3);
  const int oK01 = sig * 64 + (((l4 + 4) ^ s0_) << 3);
  const int oK10 = (sig + 4) * 64 + ((l4 ^ s4_) << 3);
  const int oK11 = (sig + 4) * 64 + (((l4 + 4) ^ s4_) << 3);
  int oV[4][2];
#pragma unroll
  for (int df = 0; df < 4; ++df) {
    const int r = df * 16 + l15;
    const int sv = ((r & 7) ^ ((2 * (r >> 3)) & 7)) & 7;
    oV[df][0] = r * 64 + ((l4 ^ sv) << 3);
    oV[df][1] = r * 64 + (((l4 + 4) ^ sv) << 3);
  }

  short8 qf[2][2];
  int bq[2];
#pragma unroll
  for (int g = 0; g < 2; ++g) {
    int qr = qbase + g * 16 + l15; if (qr > 576) qr = 576;
    bq[g] = qr;
    qf[g][0] = *(const short8*)(qh + qr * 64 + l4 * 8);
    qf[g][1] = *(const short8*)(qh + qr * 64 + 32 + l4 * 8);
  }

  // ---- init with kv = 576 column ----
  float m[2], lsum[2] = {1.f, 1.f};
  {
    const u16* kp = kh + 576 * 64 + l4 * 8;
    const short8 kA = *(const short8*)(kp);
    const short8 kB = *(const short8*)(kp + 32);
#pragma unroll
    for (int g = 0; g < 2; ++g) {
      float acc = 0.f;
#pragma unroll
      for (int j = 0; j < 8; ++j)
        acc += bf2f((u16)qf[g][0][j]) * bf2f((u16)kA[j]) +
               bf2f((u16)qf[g][1][j]) * bf2f((u16)kB[j]);
      acc += __shfl_xor(acc, 16);
      acc += __shfl_xor(acc, 32);
      m[g] = acc + b576[bq[g]];
    }
  }
  floatx4 o[2][4];
#pragma unroll
  for (int df = 0; df < 4; ++df)
#pragma unroll
    for (int i = 0; i < 4; ++i) {
      const float v5 = bf2f(vh[(size_t)(df * 16 + l4 * 4 + i) * 608 + 576]);
      o[0][df][i] = v5; o[1][df][i] = v5;
    }

  // prologue: stage tile 0
  gload16(kh + (size_t)sr * 64 + scol, &Ks[0][sr * 64 + sb * 8]);
  gload16(kh + (size_t)(sr + 32) * 64 + scol, &Ks[0][(sr + 32) * 64 + sb * 8]);
  gload16(vh + (size_t)sr * 608 + scol, &Vs[0][sr * 64 + sb * 8]);
  gload16(vh + (size_t)(sr + 32) * 608 + scol, &Vs[0][(sr + 32) * 64 + sb * 8]);
  __syncthreads();

  for (int t = 0; t < 9; ++t) {
    const int cur = t & 1;
    if (t < 8) {
      const int nk = (t + 1) * 64;
      gload16(kh + (size_t)(nk + sr) * 64 + scol, &Ks[cur ^ 1][sr * 64 + sb * 8]);
      gload16(kh + (size_t)(nk + sr + 32) * 64 + scol, &Ks[cur ^ 1][(sr + 32) * 64 + sb * 8]);
      gload16(vh + (size_t)sr * 608 + nk + scol, &Vs[cur ^ 1][sr * 64 + sb * 8]);
      gload16(vh + (size_t)(sr + 32) * 608 + nk + scol, &Vs[cur ^ 1][(sr + 32) * 64 + sb * 8]);
    }

    // bias loads issued EARLY (loop top) — L2 latency hidden under ds_read+QK MFMA
    const int kba = t * 8 + l4;
    const uint4 ba0 = *(const uint4*)(bp + ((size_t)kba * 577 + bq[0]) * 8);
    const uint4 bb0 = *(const uint4*)(bp + ((size_t)(kba + 4) * 577 + bq[0]) * 8);
    const uint4 ba1 = *(const uint4*)(bp + ((size_t)kba * 577 + bq[1]) * 8);
    const uint4 bb1 = *(const uint4*)(bp + ((size_t)(kba + 4) * 577 + bq[1]) * 8);

    const u16* kb_ = &Ks[cur][0];
    const short8 K00 = *(const short8*)(kb_ + oK00);
    const short8 K01 = *(const short8*)(kb_ + oK01);
    const short8 K10 = *(const short8*)(kb_ + oK10);
    const short8 K11 = *(const short8*)(kb_ + oK11);
    const short8 K20 = *(const short8*)(kb_ + oK00 + 32 * 64);
    const short8 K21 = *(const short8*)(kb_ + oK01 + 32 * 64);
    const short8 K30 = *(const short8*)(kb_ + oK10 + 32 * 64);
    const short8 K31 = *(const short8*)(kb_ + oK11 + 32 * 64);

    floatx4 sA0[2], sA1[2], sB0[2], sB1[2];
    __builtin_amdgcn_s_setprio(1);
#pragma unroll
    for (int g = 0; g < 2; ++g) {
      floatx4 a0 = 0.f, a1 = 0.f, b0 = 0.f, b1 = 0.f;
      a0 = MFMA16(K00, qf[g][0], a0); a0 = MFMA16(K01, qf[g][1], a0);
      a1 = MFMA16(K10, qf[g][0], a1); a1 = MFMA16(K11, qf[g][1], a1);
      b0 = MFMA16(K20, qf[g][0], b0); b0 = MFMA16(K21, qf[g][1], b0);
      b1 = MFMA16(K30, qf[g][0], b1); b1 = MFMA16(K31, qf[g][1], b1);
      sA0[g] = a0; sA1[g] = a1; sB0[g] = b0; sB1[g] = b1;
    }
    __builtin_amdgcn_s_setprio(0);

    float v_[2][16];
#pragma unroll
    for (int g = 0; g < 2; ++g) {
      const uint4 ba = (g == 0) ? ba0 : ba1;
      const uint4 bb = (g == 0) ? bb0 : bb1;
      v_[g][0] = sA0[g][0] + bflo(ba.x);  v_[g][1] = sA0[g][1] + bfhi(ba.x);
      v_[g][2] = sA0[g][2] + bflo(ba.y);  v_[g][3] = sA0[g][3] + bfhi(ba.y);
      v_[g][4] = sA1[g][0] + bflo(ba.z);  v_[g][5] = sA1[g][1] + bfhi(ba.z);
      v_[g][6] = sA1[g][2] + bflo(ba.w);  v_[g][7] = sA1[g][3] + bfhi(ba.w);
      v_[g][8]  = sB0[g][0] + bflo(bb.x); v_[g][9]  = sB0[g][1] + bfhi(bb.x);
      v_[g][10] = sB0[g][2] + bflo(bb.y); v_[g][11] = sB0[g][3] + bfhi(bb.y);
      v_[g][12] = sB1[g][0] + bflo(bb.z); v_[g][13] = sB1[g][1] + bfhi(bb.z);
      v_[g][14] = sB1[g][2] + bflo(bb.w); v_[g][15] = sB1[g][3] + bfhi(bb.w);
    }

    // tree max (depth 4)
    float vm[2];
#pragma unroll
    for (int g = 0; g < 2; ++g) {
      float m0_ = fmaxf(v_[g][0], v_[g][1]),  m1_ = fmaxf(v_[g][2], v_[g][3]);
      float m2_ = fmaxf(v_[g][4], v_[g][5]),  m3_ = fmaxf(v_[g][6], v_[g][7]);
      float m4_ = fmaxf(v_[g][8], v_[g][9]),  m5_ = fmaxf(v_[g][10], v_[g][11]);
      float m6_ = fmaxf(v_[g][12], v_[g][13]), m7_ = fmaxf(v_[g][14], v_[g][15]);
      float a = fmaxf(fmaxf(m0_, m1_), fmaxf(m2_, m3_));
      float b = fmaxf(fmaxf(m4_, m5_), fmaxf(m6_, m7_));
      a = fmaxf(a, b);
      a = fmaxf(a, __shfl_xor(a, 16));
      a = fmaxf(a, __shfl_xor(a, 32));
      vm[g] = a;
    }

    if (__any((vm[0] > m[0] + 8.f) || (vm[1] > m[1] + 8.f))) {
      const float mn0 = fmaxf(m[0], vm[0]), mn1 = fmaxf(m[1], vm[1]);
      const float sc0 = exp2hw(m[0] - mn0), sc1 = exp2hw(m[1] - mn1);
      lsum[0] *= sc0; lsum[1] *= sc1;
#pragma unroll
      for (int df = 0; df < 4; ++df) { o[0][df] *= sc0; o[1][df] *= sc1; }
      m[0] = mn0; m[1] = mn1;
    }

    union PU { unsigned u[4]; short8 s; };
    PU pA[2], pB[2];
#pragma unroll
    for (int g = 0; g < 2; ++g) {
#pragma unroll
      for (int j = 0; j < 16; ++j) v_[g][j] = exp2hw(v_[g][j] - m[g]);
      float s0 = (v_[g][0] + v_[g][1]) + (v_[g][2] + v_[g][3]);
      float s1 = (v_[g][4] + v_[g][5]) + (v_[g][6] + v_[g][7]);
      float s2 = (v_[g][8] + v_[g][9]) + (v_[g][10] + v_[g][11]);
      float s3 = (v_[g][12] + v_[g][13]) + (v_[g][14] + v_[g][15]);
      float rs = (s0 + s1) + (s2 + s3);
      rs += __shfl_xor(rs, 16);
      rs += __shfl_xor(rs, 32);
      lsum[g] += rs;
#pragma unroll
      for (int j = 0; j < 4; ++j) {
        pA[g].u[j] = cvtpk_bf16(v_[g][2 * j], v_[g][2 * j + 1]);
        pB[g].u[j] = cvtpk_bf16(v_[g][8 + 2 * j], v_[g][8 + 2 * j + 1]);
      }
    }

    const u16* vb_ = &Vs[cur][0];
    const short8 vA0 = *(const short8*)(vb_ + oV[0][0]);
    const short8 vB0 = *(const short8*)(vb_ + oV[0][1]);
    const short8 vA1 = *(const short8*)(vb_ + oV[1][0]);
    const short8 vB1 = *(const short8*)(vb_ + oV[1][1]);
    const short8 vA2 = *(const short8*)(vb_ + oV[2][0]);
    const short8 vB2 = *(const short8*)(vb_ + oV[2][1]);
    const short8 vA3 = *(const short8*)(vb_ + oV[3][0]);
    const short8 vB3 = *(const short8*)(vb_ + oV[3][1]);

    __builtin_amdgcn_s_setprio(1);
#pragma unroll
    for (int g = 0; g < 2; ++g) {
      o[g][0] = MFMA16(vA0, pA[g].s, o[g][0]); o[g][0] = MFMA16(vB0, pB[g].s, o[g][0]);
      o[g][1] = MFMA16(vA1, pA[g].s, o[g][1]); o[g][1] = MFMA16(vB1, pB[g].s, o[g][1]);
      o[g][2] = MFMA16(vA2, pA[g].s, o[g][2]); o[g][2] = MFMA16(vB2, pB[g].s, o[g][2]);
      o[g][3] = MFMA16(vA3, pA[g].s, o[g][3]); o[g][3] = MFMA16(vB3, pB[g].s, o[g][3]);
    }
    __builtin_amdgcn_s_setprio(0);

    __syncthreads();
  }

  const int b = bh / 12, h = bh - (bh / 12) * 12;
#pragma unroll
  for (int g = 0; g < 2; ++g) {
    const int gq = qbase + g * 16 + l15;
    if (gq < 577) {
      const float inv = 1.f / lsum[g];
      u16* op = xa + ((size_t)(b * 577 + gq)) * 768 + h * 64 + l4 * 4;
#pragma unroll
      for (int d = 0; d < 4; ++d) {
        unsigned w0 = cvtpk_bf16(o[g][d][0] * inv, o[g][d][1] * inv);
        unsigned w1 = cvtpk_bf16(o[g][d][2] * inv, o[g][d][3] * inv);
        *(unsigned*)(op + d * 16) = w0;
        *(unsigned*)(op + d * 16 + 2) = w1;
      }
    }
  }
}

// ---------------- launch ----------------

extern "C" void kernel_launch(void* const* d_in, const int* in_sizes, int n_in,
                              void* d_out, int out_size, void* d_ws, size_t ws_size,
                              hipStream_t stream) {
  const float* x  = (const float*)d_in[0];
  const float* Wq = (const float*)d_in[1];
  const float* Wk = (const float*)d_in[2];
  const float* Wv = (const float*)d_in[3];
  const float* Wo = (const float*)d_in[4];
  const float* bo = (const float*)d_in[5];
  const float* bt = (const float*)d_in[6];
  float* out = (float*)d_out;

  char* ws = (char*)d_ws;
  size_t off = 0;
  auto alloc = [&](size_t bytes) {
    void* p = ws + off;
    off += (bytes + 255) & ~(size_t)255;
    return p;
  };
  u16* xb   = (u16*)alloc((size_t)18464 * 768 * 2);   // reused as xa after GEMM0
  u16* WT   = (u16*)alloc((size_t)2304 * 768 * 2);
  u16* WoT  = (u16*)alloc((size_t)768 * 768 * 2);
  u16* qa   = (u16*)alloc((size_t)384 * 577 * 64 * 2);
  u16* ka   = (u16*)alloc((size_t)384 * 577 * 64 * 2);
  u16* vT   = (u16*)alloc((size_t)384 * 64 * 608 * 2);
  u16* biasPk = (u16*)alloc((size_t)76 * 577 * 8 * 2);
  float* b576 = (float*)alloc((size_t)577 * 4);
  (void)ws_size; (void)in_sizes; (void)n_in; (void)out_size;

  cvt_x_kernel<<<(18464 * 768 / 4 + 255) / 256, 256, 0, stream>>>(x, xb, 18464 * 768 / 4);
  dim3 tg4(12, 12, 4);
  cvt_wT4_kernel<<<tg4, 256, 0, stream>>>(Wq, Wk, Wv, Wo, WT, WoT);
  bias_kernel<<<(577 * 76 + 577 + 255) / 256, 256, 0, stream>>>(bt, biasPk, b576);

  // QKV projection: [18464][768] x [768][2304]; 256x256 tiles -> 73 x 9 blocks
  gemm_kernel<0><<<73 * 9, 512, 0, stream>>>(xb, WT, 18464, 9,
                                             nullptr, nullptr, qa, ka, vT);
  // attention -> xa (reuse xb region)
  attn_kernel<<<1920, 256, 0, stream>>>(qa, ka, vT, biasPk, b576, xb);
  // output projection: xa x WoT + bo -> out (f32); 73 x 3 blocks
  gemm_kernel<1><<<73 * 3, 512, 0, stream>>>(xb, WoT, 18464, 3,
                                             out, bo, nullptr, nullptr, nullptr);
}